// Round 4
// baseline (232.933 us; speedup 1.0000x reference)
//
#include <hip/hip_runtime.h>
#include <stdint.h>

// SoftPerspectiveShader: barycentric texture sampling + softmax RGB blend.
// N=4, H=W=512, K=8, F=200000. 
//
// R1: gate gather on weight magnitude (zbuf sorted -> ~1.01 live frags/pixel).
//     192 -> 82 us.
// R2: 7-bit packed color table (1.6 MB, L2-resident), single dwordx2 gather.
//     FETCH 162->121 MB, time unchanged (82 us) -> NOT bw/gather-latency bound.
// R3: the 82 us floor is invariant to traffic and instruction count; timed
//     replays read everything from L3 and still take 82 us. Hypothesis:
//     workgroup-launch-rate / per-wave-overhead floor (4096 tiny wgs, ~49
//     cy/wg) + ~2 lines in flight per wave. Fix: 1024 persistent wgs, 4
//     pixels/thread, 2-stage software pipeline (load pixel i+1 while
//     processing pixel i).

#define KFRAG 8
#define PPT   4    // pixels per thread
#define WGS   256

struct PixVec {
    int4   f0, f1;
    float4 z0, z1;
    float4 d0, d1;
    float4 bq0;
};

__device__ __forceinline__ PixVec load_pix(
    const int* __restrict__ p2f, const float* __restrict__ bary,
    const float* __restrict__ zbuf, const float* __restrict__ dists, int p)
{
    PixVec v;
    const int4* p2f4 = (const int4*)p2f + (size_t)p * 2;
    v.f0 = p2f4[0];
    v.f1 = p2f4[1];
    const float4* zb4 = (const float4*)zbuf + (size_t)p * 2;
    v.z0 = zb4[0];
    v.z1 = zb4[1];
    const float4* dd4 = (const float4*)dists + (size_t)p * 2;
    v.d0 = dd4[0];
    v.d1 = dd4[1];
    v.bq0 = ((const float4*)bary)[(size_t)p * 6]; // bary[k=0][0..2]
    return v;
}

__device__ __forceinline__ void unpack_texel(uint2 g, float b0, float b1, float b2,
                                             float& tr, float& tg, float& tb)
{
    uint64_t v = ((uint64_t)g.y << 32) | g.x;
    float c[9];
#pragma unroll
    for (int i = 0; i < 9; ++i)
        c[i] = (float)((uint32_t)(v >> (7 * i)) & 127u) * (1.0f / 127.0f);
    tr = fmaf(b0, c[0], fmaf(b1, c[3], b2 * c[6]));
    tg = fmaf(b0, c[1], fmaf(b1, c[4], b2 * c[7]));
    tb = fmaf(b0, c[2], fmaf(b1, c[5], b2 * c[8]));
}

__device__ __forceinline__ void process_pix(
    const PixVec& v, const float* __restrict__ bary,
    const uint2* __restrict__ tab, float* __restrict__ out, int p)
{
    constexpr float SIGMA_INV = 1.0f / 1e-4f;
    constexpr float GAMMA_INV = 1.0f / 1e-4f;
    constexpr float EPS   = 1e-10f;
    constexpr float ZNEAR = 1.0f;
    constexpr float ZFAR  = 100.0f;
    constexpr float ZCUT  = -1.2e-3f; // weight < 1e-5 => contribution < 1e-5

    // unconditional k=0 gather: issues immediately (p2f already in regs)
    int idx0 = v.f0.x > 0 ? v.f0.x : 0;
    uint2 g0 = tab[idx0];

    int   fid[KFRAG] = {v.f0.x, v.f0.y, v.f0.z, v.f0.w,
                        v.f1.x, v.f1.y, v.f1.z, v.f1.w};
    float zb[KFRAG]  = {v.z0.x, v.z0.y, v.z0.z, v.z0.w,
                        v.z1.x, v.z1.y, v.z1.z, v.z1.w};
    float dd[KFRAG]  = {v.d0.x, v.d0.y, v.d0.z, v.d0.w,
                        v.d1.x, v.d1.y, v.d1.z, v.d1.w};

    float prob[KFRAG], zinv[KFRAG];
    float zmax = EPS;
#pragma unroll
    for (int k = 0; k < KFRAG; ++k) {
        float m = (fid[k] >= 0) ? 1.0f : 0.0f;
        prob[k] = m / (1.0f + __expf(dd[k] * SIGMA_INV));
        zinv[k] = m * ((ZFAR - zb[k]) * (1.0f / (ZFAR - ZNEAR)));
        zmax = fmaxf(zmax, zinv[k]);
    }

    float delta = fmaxf(__expf((EPS - zmax) * GAMMA_INV), EPS);
    float denom = delta;
    float r = 0.0f, g = 0.0f, b = 0.0f;
    float keep = 1.0f;
#pragma unroll
    for (int k = 0; k < KFRAG; ++k) keep *= (1.0f - prob[k]);

    { // k=0 contribution (weight is 0 if invalid/occluded)
        float w = prob[0] * __expf((zinv[0] - zmax) * GAMMA_INV);
        float tr, tg, tb;
        unpack_texel(g0, v.bq0.x, v.bq0.y, v.bq0.z, tr, tg, tb);
        denom += w;
        r = fmaf(w, tr, r);
        g = fmaf(w, tg, g);
        b = fmaf(w, tb, b);
    }

    // rare k>=1 survivors (~1% of pixels): execz-skipped
#pragma unroll
    for (int k = 1; k < KFRAG; ++k) {
        if ((fid[k] >= 0) && (zinv[k] - zmax > ZCUT)) {
            float w = prob[k] * __expf((zinv[k] - zmax) * GAMMA_INV);
            uint2 gk = tab[fid[k]];
            const float* bp = bary + (size_t)p * 24 + k * 3;
            float b0 = bp[0], b1 = bp[1], b2 = bp[2];
            float tr, tg, tb;
            unpack_texel(gk, b0, b1, b2, tr, tg, tb);
            denom += w;
            r = fmaf(w, tr, r);
            g = fmaf(w, tg, g);
            b = fmaf(w, tb, b);
        }
    }

    float inv = 1.0f / denom;
    float4 o;
    o.x = (r + delta) * inv; // background = (1,1,1)
    o.y = (g + delta) * inv;
    o.z = (b + delta) * inv;
    o.w = keep;
    ((float4*)out)[p] = o;
}

__global__ __launch_bounds__(WGS) void pack_faces_kernel(
    const float* __restrict__ fc, uint2* __restrict__ tab, int F)
{
    int f = blockIdx.x * blockDim.x + threadIdx.x;
    if (f >= F) return;
    const float* p = fc + (size_t)f * 9;
    uint64_t acc = 0;
#pragma unroll
    for (int i = 0; i < 9; ++i) {
        float c = p[i];
        int q = (int)fmaf(c, 127.0f, 0.5f);
        q = q < 0 ? 0 : (q > 127 ? 127 : q);
        acc |= (uint64_t)q << (7 * i);
    }
    tab[f] = make_uint2((uint32_t)acc, (uint32_t)(acc >> 32));
}

__global__ __launch_bounds__(WGS) void soft_shader_kernel(
    const int*   __restrict__ p2f,         // [NP, 8]
    const float* __restrict__ bary,        // [NP, 8, 3]
    const float* __restrict__ zbuf,        // [NP, 8]
    const float* __restrict__ dists,       // [NP, 8]
    const uint2* __restrict__ tab,         // [F] packed 7-bit colors
    float*       __restrict__ out,         // [NP, 4]
    int NP)
{
    int tid = blockIdx.x * blockDim.x + threadIdx.x;
    int T   = gridDim.x * blockDim.x;

    int p = tid;
    if (p >= NP) return;

    PixVec cur = load_pix(p2f, bary, zbuf, dists, p);
#pragma unroll
    for (int i = 0; i < PPT; ++i) {
        int pn = p + T;
        bool more = (i + 1 < PPT) && (pn < NP);
        PixVec nxt;
        if (more) nxt = load_pix(p2f, bary, zbuf, dists, pn); // prefetch
        process_pix(cur, bary, tab, out, p);
        if (!more) break;
        cur = nxt;
        p = pn;
    }
}

extern "C" void kernel_launch(void* const* d_in, const int* in_sizes, int n_in,
                              void* d_out, int out_size, void* d_ws, size_t ws_size,
                              hipStream_t stream) {
    const int*   p2f         = (const int*)d_in[0];
    const float* bary        = (const float*)d_in[1];
    const float* zbuf        = (const float*)d_in[2];
    const float* dists       = (const float*)d_in[3];
    const float* face_colors = (const float*)d_in[4];
    float* out = (float*)d_out;

    int NP = in_sizes[0] / KFRAG; // N*H*W pixels
    int F  = in_sizes[4] / 9;

    uint2* tab = (uint2*)d_ws;
    pack_faces_kernel<<<(F + WGS - 1) / WGS, WGS, 0, stream>>>(face_colors, tab, F);

    int grid = (NP + WGS * PPT - 1) / (WGS * PPT); // 1024 wgs for 1M pixels
    soft_shader_kernel<<<grid, WGS, 0, stream>>>(
        p2f, bary, zbuf, dists, tab, out, NP);
}

// Round 5
// 232.800 us; speedup vs baseline: 1.0006x; 1.0006x over previous
//
#include <hip/hip_runtime.h>
#include <stdint.h>

// SoftPerspectiveShader: barycentric texture sampling + softmax RGB blend.
// N=4, H=W=512, K=8, F=200000.
//
// R1: gate gather on weight magnitude (zbuf sorted -> ~1.01 live frags/px).
//     192 -> 82 us.
// R2: 7-bit packed color table (1.6 MB, L2-resident), single dwordx2 gather.
//     FETCH 162->121 MB, time unchanged -> not BW-bound.
// R3: persistent grid + prefetch loop: unchanged (82 us). VGPR=44 proves the
//     compiler sank the prefetch (needs >=56 regs live) -> pipeline never
//     existed. Floor invariant to wg count, traffic, instr count.
// R4: force real memory-level parallelism: PPT=2 straight-line batch (all 14
//     streaming loads + both k=0 gathers in flight before any math), with
//     __launch_bounds__(256,4) to ALLOW ~100 VGPR so the batch stays live.
//     Replace 8 IEEE divides/pixel with v_rcp_f32.

#define KFRAG 8
#define WGS   256
#define PPT   2

__device__ __forceinline__ float rcp_fast(float x) {
    return __builtin_amdgcn_rcpf(x);
}

struct Pix {
    int4   f0, f1;
    float4 z0, z1;
    float4 d0, d1;
    float4 bq0;
};

__device__ __forceinline__ Pix load_pix(
    const int* __restrict__ p2f, const float* __restrict__ bary,
    const float* __restrict__ zbuf, const float* __restrict__ dists, int p)
{
    Pix v;
    const int4* p2f4 = (const int4*)p2f + (size_t)p * 2;
    v.f0 = p2f4[0];
    v.f1 = p2f4[1];
    const float4* zb4 = (const float4*)zbuf + (size_t)p * 2;
    v.z0 = zb4[0];
    v.z1 = zb4[1];
    const float4* dd4 = (const float4*)dists + (size_t)p * 2;
    v.d0 = dd4[0];
    v.d1 = dd4[1];
    v.bq0 = ((const float4*)bary)[(size_t)p * 6]; // bary[k=0][0..2]
    return v;
}

__device__ __forceinline__ void unpack_texel(uint2 g, float b0, float b1, float b2,
                                             float& tr, float& tg, float& tb)
{
    uint64_t v = ((uint64_t)g.y << 32) | g.x;
    float c[9];
#pragma unroll
    for (int i = 0; i < 9; ++i)
        c[i] = (float)((uint32_t)(v >> (7 * i)) & 127u) * (1.0f / 127.0f);
    tr = fmaf(b0, c[0], fmaf(b1, c[3], b2 * c[6]));
    tg = fmaf(b0, c[1], fmaf(b1, c[4], b2 * c[7]));
    tb = fmaf(b0, c[2], fmaf(b1, c[5], b2 * c[8]));
}

__global__ __launch_bounds__(WGS) void pack_faces_kernel(
    const float* __restrict__ fc, uint2* __restrict__ tab, int F)
{
    int f = blockIdx.x * blockDim.x + threadIdx.x;
    if (f >= F) return;
    const float* p = fc + (size_t)f * 9;
    uint64_t acc = 0;
#pragma unroll
    for (int i = 0; i < 9; ++i) {
        float c = p[i];
        int q = (int)fmaf(c, 127.0f, 0.5f);
        q = q < 0 ? 0 : (q > 127 ? 127 : q);
        acc |= (uint64_t)q << (7 * i);
    }
    tab[f] = make_uint2((uint32_t)acc, (uint32_t)(acc >> 32));
}

__global__ __launch_bounds__(WGS, 4) void soft_shader_kernel(
    const int*   __restrict__ p2f,         // [NP, 8]
    const float* __restrict__ bary,        // [NP, 8, 3]
    const float* __restrict__ zbuf,        // [NP, 8]
    const float* __restrict__ dists,       // [NP, 8]
    const uint2* __restrict__ tab,         // [F] packed 7-bit colors
    float*       __restrict__ out,         // [NP, 4]
    int NP)
{
    constexpr float SIGMA_INV = 1.0f / 1e-4f;
    constexpr float GAMMA_INV = 1.0f / 1e-4f;
    constexpr float EPS   = 1e-10f;
    constexpr float ZNEAR = 1.0f;
    constexpr float ZFAR  = 100.0f;
    constexpr float ZCUT  = -1.2e-3f; // weight < 1e-5 => contribution < 1e-5

    int tid = blockIdx.x * WGS + threadIdx.x;
    int T   = gridDim.x * WGS;

    int pix[PPT];
#pragma unroll
    for (int j = 0; j < PPT; ++j) pix[j] = tid + j * T;

    // ---- phase 1: ALL streaming loads for both pixels, back-to-back ----
    Pix v[PPT];
#pragma unroll
    for (int j = 0; j < PPT; ++j) {
        if (pix[j] < NP) v[j] = load_pix(p2f, bary, zbuf, dists, pix[j]);
    }

    // ---- phase 2: both k=0 gathers (only depend on the p2f loads) ----
    uint2 g0[PPT];
#pragma unroll
    for (int j = 0; j < PPT; ++j) {
        if (pix[j] < NP) {
            int idx0 = v[j].f0.x > 0 ? v[j].f0.x : 0;
            g0[j] = tab[idx0];
        }
    }

    // ---- phase 3: math + blend + store per pixel ----
#pragma unroll
    for (int j = 0; j < PPT; ++j) {
        if (pix[j] >= NP) continue;
        int p = pix[j];

        int   fid[KFRAG] = {v[j].f0.x, v[j].f0.y, v[j].f0.z, v[j].f0.w,
                            v[j].f1.x, v[j].f1.y, v[j].f1.z, v[j].f1.w};
        float zb[KFRAG]  = {v[j].z0.x, v[j].z0.y, v[j].z0.z, v[j].z0.w,
                            v[j].z1.x, v[j].z1.y, v[j].z1.z, v[j].z1.w};
        float dd[KFRAG]  = {v[j].d0.x, v[j].d0.y, v[j].d0.z, v[j].d0.w,
                            v[j].d1.x, v[j].d1.y, v[j].d1.z, v[j].d1.w};

        float prob[KFRAG], zinv[KFRAG];
        float zmax = EPS;
#pragma unroll
        for (int k = 0; k < KFRAG; ++k) {
            float m = (fid[k] >= 0) ? 1.0f : 0.0f;
            prob[k] = m * rcp_fast(1.0f + __expf(dd[k] * SIGMA_INV));
            zinv[k] = m * ((ZFAR - zb[k]) * (1.0f / (ZFAR - ZNEAR)));
            zmax = fmaxf(zmax, zinv[k]);
        }

        float delta = fmaxf(__expf((EPS - zmax) * GAMMA_INV), EPS);
        float denom = delta;
        float r = 0.0f, g = 0.0f, b = 0.0f;
        float keep = 1.0f;
#pragma unroll
        for (int k = 0; k < KFRAG; ++k) keep *= (1.0f - prob[k]);

        { // k=0 contribution (weight is 0 if invalid/occluded)
            float w = prob[0] * __expf((zinv[0] - zmax) * GAMMA_INV);
            float tr, tg, tb;
            unpack_texel(g0[j], v[j].bq0.x, v[j].bq0.y, v[j].bq0.z, tr, tg, tb);
            denom += w;
            r = fmaf(w, tr, r);
            g = fmaf(w, tg, g);
            b = fmaf(w, tb, b);
        }

        // rare k>=1 survivors (~1% of pixels): execz-skipped
#pragma unroll
        for (int k = 1; k < KFRAG; ++k) {
            if ((fid[k] >= 0) && (zinv[k] - zmax > ZCUT)) {
                float w = prob[k] * __expf((zinv[k] - zmax) * GAMMA_INV);
                uint2 gk = tab[fid[k]];
                const float* bp = bary + (size_t)p * 24 + k * 3;
                float b0 = bp[0], b1 = bp[1], b2 = bp[2];
                float tr, tg, tb;
                unpack_texel(gk, b0, b1, b2, tr, tg, tb);
                denom += w;
                r = fmaf(w, tr, r);
                g = fmaf(w, tg, g);
                b = fmaf(w, tb, b);
            }
        }

        float inv = rcp_fast(denom);
        float4 o;
        o.x = (r + delta) * inv; // background = (1,1,1)
        o.y = (g + delta) * inv;
        o.z = (b + delta) * inv;
        o.w = keep;
        ((float4*)out)[p] = o;
    }
}

extern "C" void kernel_launch(void* const* d_in, const int* in_sizes, int n_in,
                              void* d_out, int out_size, void* d_ws, size_t ws_size,
                              hipStream_t stream) {
    const int*   p2f         = (const int*)d_in[0];
    const float* bary        = (const float*)d_in[1];
    const float* zbuf        = (const float*)d_in[2];
    const float* dists       = (const float*)d_in[3];
    const float* face_colors = (const float*)d_in[4];
    float* out = (float*)d_out;

    int NP = in_sizes[0] / KFRAG; // N*H*W pixels
    int F  = in_sizes[4] / 9;

    uint2* tab = (uint2*)d_ws;
    pack_faces_kernel<<<(F + WGS - 1) / WGS, WGS, 0, stream>>>(face_colors, tab, F);

    int grid = (NP + WGS * PPT - 1) / (WGS * PPT); // 2048 wgs
    soft_shader_kernel<<<grid, WGS, 0, stream>>>(
        p2f, bary, zbuf, dists, tab, out, NP);
}